// Round 1
// baseline (6495.279 us; speedup 1.0000x reference)
//
#include <hip/hip_runtime.h>
#include <hip/hip_bf16.h>

// ---------------- problem constants ----------------
#define NB   16          // batch
#define C1   128         // conv1 out channels
#define XS   29          // input spatial
#define HS   27          // h spatial (29-3+1)
#define HSP  19683       // 27^3
#define PS   10          // pcaps out spatial
#define PSP  1000        // 10^3
#define PC   128         // pcaps out channels
#define RR   16000       // R = 16*1000
#define NCAP 2
#define KTAP 729         // 9^3
#define MTOT 16000       // NB*PSP
#define HTOT 40310784L   // NB*HSP*C1

// ---------------- workspace layout (floats) ----------------
#define OFF_WT   0UL                       // 93312*128 = 11,943,936
#define OFF_H    11943936UL                // 40,310,784
#define OFF_P    52254720UL                // 2,048,000   p[b][sp][oc]
#define OFF_U    54302720UL                // 2,048,000   u[b][r][8]
#define OFF_PRI  56350720UL                // 8,192,000   priors[b][c][r][16]
#define OFF_LOG  64542720UL                // 512,000     logits[b][c][r]
#define OFF_S    65054720UL                // 512
#define OFF_V    65055232UL                // 512
#define OFF_D0   65055744UL                // 512
#define OFF_D1   65056256UL                // 8192
#define OFF_D2   65064448UL                // 32768
#define OFF_D3   65097216UL                // 163840
#define OFF_D4   65261056UL                // 432000

// ============ prep: wT[tap*128+ic][oc] = pcaps_w[oc][ic][tap] ============
__global__ void prep_wT(const float* __restrict__ w, float* __restrict__ wT) {
    __shared__ float tile[32][33];
    int tap0 = blockIdx.x * 32;
    int oc0  = blockIdx.y * 32;
    int ic   = blockIdx.z;
    int tx = threadIdx.x & 31, ty = threadIdx.x >> 5;   // 32 x 8
    #pragma unroll
    for (int j = 0; j < 32; j += 8) {
        int tap = tap0 + tx, oc = oc0 + ty + j;
        if (tap < KTAP) tile[ty + j][tx] = w[(size_t)oc * 93312 + (size_t)ic * KTAP + tap];
    }
    __syncthreads();
    #pragma unroll
    for (int j = 0; j < 32; j += 8) {
        int tap = tap0 + ty + j, oc = oc0 + tx;
        if (tap < KTAP) wT[((size_t)tap * 128 + ic) * 128 + oc] = tile[tx][ty + j];
    }
}

// ============ conv1 3x3x3 stride1 + bias + relu, h channel-last ============
__global__ void conv1_relu(const float* __restrict__ x, const float* __restrict__ w,
                           const float* __restrict__ bias, float* __restrict__ h) {
    __shared__ float wl[27][128];
    int t = threadIdx.x;
    for (int i = t; i < 27 * 128; i += 256) wl[i % 27][i / 27] = w[i];
    __syncthreads();
    long gid = (long)blockIdx.x * 256 + t;     // over NB*HSP*C1, grid exact
    int c   = (int)(gid & 127);
    int spz = (int)(gid >> 7);                 // b*HSP + z*729 + y*27 + xx
    int b = spz / HSP, sp = spz % HSP;
    int z = sp / 729, y = (sp / 27) % 27, xx = sp % 27;
    const float* xb = x + (size_t)b * (XS * XS * XS);
    float acc = bias[c];
    #pragma unroll
    for (int dz = 0; dz < 3; dz++)
        #pragma unroll
        for (int dy = 0; dy < 3; dy++)
            #pragma unroll
            for (int dx = 0; dx < 3; dx++)
                acc += xb[((z + dz) * XS + (y + dy)) * XS + (xx + dx)] * wl[(dz * 3 + dy) * 3 + dx][c];
    h[gid] = fmaxf(acc, 0.f);
}

// ============ pcaps implicit GEMM (fp32), M-tile 128, K-split 8 by tap ============
// p[b][sp][oc] += sum over (tap,ic) of h[b][2oz+dz][2oy+dy][2ox+dx][ic] * wT[tap*128+ic][oc]
__global__ void pcaps_gemm(const float* __restrict__ h, const float* __restrict__ wT,
                           float* __restrict__ p) {
    __shared__ float As[128][36];
    __shared__ float Bs[32][128];
    int t  = threadIdx.x;
    int tn = t & 15;          // oc = tn*8 + j
    int tm = t >> 4;          // m = m0 + 16*i + tm
    int m0 = blockIdx.x * 128;
    int tap_begin = blockIdx.y * 92;
    int tap_end   = min(KTAP, tap_begin + 92);

    int rowbase[4]; int rowm[4]; int c4v[4]; int rowv[4];
    #pragma unroll
    for (int q = 0; q < 4; q++) {
        int idx = q * 256 + t; int row = idx >> 3, c4 = idx & 7;
        int m = m0 + row; int b = m / PSP, sp = m % PSP;
        int oz = sp / 100, oy = (sp / 10) % 10, ox = sp % 10;
        rowbase[q] = (((b * HS + 2 * oz) * HS + 2 * oy) * HS + 2 * ox) * 128 + c4 * 4;
        rowm[q] = m; c4v[q] = c4; rowv[q] = row;
    }

    float acc[8][8];
    #pragma unroll
    for (int i = 0; i < 8; i++)
        #pragma unroll
        for (int j = 0; j < 8; j++) acc[i][j] = 0.f;

    for (int tap = tap_begin; tap < tap_end; ++tap) {
        int dz = tap / 81, dy = (tap / 9) % 9, dx = tap % 9;
        int tapoff = ((dz * HS + dy) * HS + dx) * 128;
        for (int ic0 = 0; ic0 < 128; ic0 += 32) {
            #pragma unroll
            for (int q = 0; q < 4; q++) {
                const float4 vv = *(const float4*)&h[(size_t)rowbase[q] + tapoff + ic0];
                *(float4*)&As[rowv[q]][c4v[q] * 4] = vv;
            }
            const float4* bsrc = (const float4*)&wT[((size_t)tap * 128 + ic0) * 128];
            #pragma unroll
            for (int q = 0; q < 4; q++) ((float4*)Bs)[q * 256 + t] = bsrc[q * 256 + t];
            __syncthreads();
            #pragma unroll 8
            for (int k = 0; k < 32; ++k) {
                float a[8], bb[8];
                #pragma unroll
                for (int i = 0; i < 2; i++) {
                    float4 v4 = *(const float4*)&Bs[k][tn * 8 + i * 4];
                    bb[i*4+0] = v4.x; bb[i*4+1] = v4.y; bb[i*4+2] = v4.z; bb[i*4+3] = v4.w;
                }
                #pragma unroll
                for (int i = 0; i < 8; i++) a[i] = As[16 * i + tm][k];
                #pragma unroll
                for (int i = 0; i < 8; i++)
                    #pragma unroll
                    for (int j = 0; j < 8; j++) acc[i][j] += a[i] * bb[j];
            }
            __syncthreads();
        }
    }
    #pragma unroll
    for (int i = 0; i < 8; i++) {
        int m = m0 + 16 * i + tm;
        #pragma unroll
        for (int j = 0; j < 8; j++)
            atomicAdd(&p[(size_t)m * 128 + tn * 8 + j], acc[i][j]);
    }
}

// ============ squash over capsule-dim 8 -> u[b][r][8] ============
__global__ void squash_u(const float* __restrict__ p, const float* __restrict__ pb,
                         float* __restrict__ u) {
    int gid = blockIdx.x * 256 + threadIdx.x;      // NB*RR = 256000, exact grid
    int b = gid / RR, r = gid % RR;
    int s = r % PSP, rq = r / PSP;
    float vals[8]; float ss = 0.f;
    #pragma unroll
    for (int i = 0; i < 8; i++) {
        int ch = i * 16 + rq;
        float pv = p[((size_t)b * PSP + s) * 128 + ch] + pb[ch];
        vals[i] = pv; ss += pv * pv;
    }
    float n = sqrtf(ss);
    float scale = ss / (1.f + ss) / (n + 1e-8f);
    #pragma unroll
    for (int i = 0; i < 8; i++) u[(size_t)gid * 8 + i] = vals[i] * scale;
}

// ============ priors[b][c][r][16] = sum_i u[b][r][i] * rw[c][r][i][16] ============
__global__ void priors_k(const float* __restrict__ u, const float* __restrict__ rw,
                         float* __restrict__ pri) {
    __shared__ float wl[16][132];
    int bx = blockIdx.x; int c = bx / 1000; int r0 = (bx % 1000) * 16;
    int t = threadIdx.x;
    const float4* src = (const float4*)(rw + ((size_t)c * RR + r0) * 128);
    #pragma unroll
    for (int q = 0; q < 8; q++) {
        int idx = q * 256 + t;
        int row = idx >> 5, c4 = idx & 31;
        *(float4*)&wl[row][c4 * 4] = src[idx];
    }
    __syncthreads();
    int bb = t >> 4, rl = t & 15;
    const float* up = u + ((size_t)bb * RR + r0 + rl) * 8;
    float4 u0 = *(const float4*)up, u1 = *(const float4*)(up + 4);
    float uu[8] = {u0.x, u0.y, u0.z, u0.w, u1.x, u1.y, u1.z, u1.w};
    float out[16];
    #pragma unroll
    for (int o = 0; o < 16; o++) out[o] = 0.f;
    #pragma unroll
    for (int i = 0; i < 8; i++)
        #pragma unroll
        for (int o = 0; o < 16; o++) out[o] += uu[i] * wl[rl][i * 16 + o];
    float* dst = pri + ((size_t)(bb * 2 + c) * RR + r0 + rl) * 16;
    #pragma unroll
    for (int q = 0; q < 4; q++)
        *(float4*)&dst[q * 4] = make_float4(out[q*4], out[q*4+1], out[q*4+2], out[q*4+3]);
}

// ============ routing: s[b][c][16] = sum_r softmax_c(logits) * priors ============
__global__ void route_s(const float* __restrict__ pri, const float* __restrict__ lg,
                        float* __restrict__ s) {
    int b = blockIdx.x, chunk = blockIdx.y;
    int t = threadIdx.x, o = t & 15, rl = t >> 4;
    float acc0 = 0.f, acc1 = 0.f;
    for (int j = 0; j < 40; j++) {
        int r = chunk * 640 + j * 16 + rl;
        float l0 = lg[(size_t)(b * 2 + 0) * RR + r];
        float l1 = lg[(size_t)(b * 2 + 1) * RR + r];
        float m = fmaxf(l0, l1);
        float e0 = __expf(l0 - m), e1 = __expf(l1 - m);
        float inv = 1.f / (e0 + e1);
        acc0 += (e0 * inv) * pri[((size_t)(b * 2 + 0) * RR + r) * 16 + o];
        acc1 += (e1 * inv) * pri[((size_t)(b * 2 + 1) * RR + r) * 16 + o];
    }
    __shared__ float red[2][16][17];
    red[0][rl][o] = acc0; red[1][rl][o] = acc1;
    __syncthreads();
    for (int step = 8; step >= 1; step >>= 1) {
        if (rl < step) {
            red[0][rl][o] += red[0][rl + step][o];
            red[1][rl][o] += red[1][rl + step][o];
        }
        __syncthreads();
    }
    if (rl == 0) {
        atomicAdd(&s[(b * 2 + 0) * 16 + o], red[0][0][o]);
        atomicAdd(&s[(b * 2 + 1) * 16 + o], red[1][0][o]);
    }
}

__global__ void squash_v(const float* __restrict__ s, float* __restrict__ v) {
    int t = threadIdx.x;            // 512 = 32 bc * 16 o
    int bc = t >> 4, o = t & 15;
    float ss = 0.f;
    #pragma unroll
    for (int i = 0; i < 16; i++) { float x = s[bc * 16 + i]; ss += x * x; }
    float n = sqrtf(ss);
    float sc = ss / (1.f + ss) / (n + 1e-8f);
    v[bc * 16 + o] = s[bc * 16 + o] * sc;
}

__global__ void route_logit(const float* __restrict__ pri, const float* __restrict__ v,
                            float* __restrict__ lg) {
    int gid = blockIdx.x * 256 + threadIdx.x;    // 512000 exact
    int bc = gid / RR;
    const float* pp = pri + (size_t)gid * 16;
    float dot = 0.f;
    #pragma unroll
    for (int o = 0; o < 16; o++) dot += pp[o] * v[bc * 16 + o];
    lg[gid] += dot;
}

// ============ classes + argmax mask -> d0[16][32], classes -> d_out[0:32] ============
__global__ void classes_mask(const float* __restrict__ v, float* __restrict__ out,
                             float* __restrict__ d0) {
    __shared__ float cls[32];
    int t = threadIdx.x;
    if (t < 32) {
        float ss = 0.f;
        #pragma unroll
        for (int i = 0; i < 16; i++) { float x = v[t * 16 + i]; ss += x * x; }
        float n = sqrtf(ss);
        cls[t] = n; out[t] = n;
    }
    __syncthreads();
    int b = t >> 5, k = t & 31, c = k >> 4;
    int win = (cls[b * 2 + 1] > cls[b * 2 + 0]) ? 1 : 0;
    d0[t] = (c == win) ? v[b * 32 + k] : 0.f;
}

// ============ decoder small layers (full-K, bias+relu) ============
template<int K>
__global__ void dec_small(const float* __restrict__ din, const float* __restrict__ W,
                          const float* __restrict__ bias, float* __restrict__ dout, int N) {
    __shared__ float dl[16 * K];
    int t = threadIdx.x;
    for (int i = t; i < 16 * K; i += 256) dl[i] = din[i];
    __syncthreads();
    int n = blockIdx.x * 256 + t;
    if (n >= N) return;
    float acc[16];
    float bv = bias[n];
    #pragma unroll
    for (int b = 0; b < 16; b++) acc[b] = bv;
    for (int k = 0; k < K; k++) {
        float w = W[(size_t)k * N + n];
        #pragma unroll
        for (int b = 0; b < 16; b++) acc[b] += dl[b * K + k] * w;
    }
    #pragma unroll
    for (int b = 0; b < 16; b++) dout[(size_t)b * N + n] = fmaxf(acc[b], 0.f);
}

// ============ decoder big layers: K-split partial GEMM (atomic) ============
__global__ void dec_split(const float* __restrict__ din, const float* __restrict__ W,
                          float* __restrict__ part, int N, int K, int KC) {
    extern __shared__ float dl[];
    int t = threadIdx.x;
    int k0 = blockIdx.y * KC;
    for (int i = t; i < 16 * KC; i += 256) {
        int b = i / KC, kk = i % KC;
        dl[i] = din[(size_t)b * K + k0 + kk];
    }
    __syncthreads();
    int n = blockIdx.x * 1024 + t;
    bool g0 = n < N, g1 = n + 256 < N, g2 = n + 512 < N, g3 = n + 768 < N;
    float acc[16][4];
    #pragma unroll
    for (int b = 0; b < 16; b++)
        #pragma unroll
        for (int j = 0; j < 4; j++) acc[b][j] = 0.f;
    const float* Wp = W + (size_t)k0 * N + n;
    for (int kk = 0; kk < KC; kk++) {
        float w0 = g0 ? Wp[0]   : 0.f;
        float w1 = g1 ? Wp[256] : 0.f;
        float w2 = g2 ? Wp[512] : 0.f;
        float w3 = g3 ? Wp[768] : 0.f;
        Wp += N;
        #pragma unroll
        for (int b = 0; b < 16; b++) {
            float dv = dl[b * KC + kk];
            acc[b][0] += dv * w0; acc[b][1] += dv * w1;
            acc[b][2] += dv * w2; acc[b][3] += dv * w3;
        }
    }
    #pragma unroll
    for (int j = 0; j < 4; j++)
        if (n + j * 256 < N)
            #pragma unroll
            for (int b = 0; b < 16; b++)
                atomicAdd(&part[(size_t)b * N + n + j * 256], acc[b][j]);
}

__global__ void bias_act(const float* __restrict__ part, const float* __restrict__ bias,
                         float* __restrict__ out, int N, int total, int sigm) {
    int gid = blockIdx.x * 256 + threadIdx.x;
    if (gid >= total) return;
    int n = gid % N;
    float x = part[gid] + bias[n];
    out[gid] = sigm ? (1.f / (1.f + __expf(-x))) : fmaxf(x, 0.f);
}

// ================================================================
extern "C" void kernel_launch(void* const* d_in, const int* in_sizes, int n_in,
                              void* d_out, int out_size, void* d_ws, size_t ws_size,
                              hipStream_t stream) {
    const float* x        = (const float*)d_in[0];
    const float* conv1_w  = (const float*)d_in[1];
    const float* conv1_b  = (const float*)d_in[2];
    const float* pcaps_w  = (const float*)d_in[3];
    const float* pcaps_b  = (const float*)d_in[4];
    const float* route_w  = (const float*)d_in[5];
    const float* dec_w1   = (const float*)d_in[6];
    const float* dec_b1   = (const float*)d_in[7];
    const float* dec_w2   = (const float*)d_in[8];
    const float* dec_b2   = (const float*)d_in[9];
    const float* dec_w3   = (const float*)d_in[10];
    const float* dec_b3   = (const float*)d_in[11];
    const float* dec_w4   = (const float*)d_in[12];
    const float* dec_b4   = (const float*)d_in[13];
    float* out = (float*)d_out;

    float* ws = (float*)d_ws;
    float* wT   = ws + OFF_WT;
    float* h    = ws + OFF_H;
    float* p    = ws + OFF_P;
    float* u    = ws + OFF_U;
    float* pri  = ws + OFF_PRI;
    float* lg   = ws + OFF_LOG;
    float* s    = ws + OFF_S;
    float* v    = ws + OFF_V;
    float* d0   = ws + OFF_D0;
    float* d1   = ws + OFF_D1;
    float* d2   = ws + OFF_D2;
    float* d3   = ws + OFF_D3;
    float* d4   = ws + OFF_D4;

    // prep + conv1
    prep_wT<<<dim3(23, 4, 128), 256, 0, stream>>>(pcaps_w, wT);
    conv1_relu<<<(int)(HTOT / 256), 256, 0, stream>>>(x, conv1_w, conv1_b, h);

    // pcaps conv (implicit GEMM, atomic K-split)
    hipMemsetAsync(p, 0, (size_t)NB * PSP * 128 * sizeof(float), stream);
    pcaps_gemm<<<dim3(125, 8), 256, 0, stream>>>(h, wT, p);

    // squash -> u ; priors einsum
    squash_u<<<1000, 256, 0, stream>>>(p, pcaps_b, u);
    priors_k<<<2000, 256, 0, stream>>>(u, route_w, pri);

    // dynamic routing, 3 iterations
    hipMemsetAsync(lg, 0, (size_t)NB * NCAP * RR * sizeof(float), stream);
    for (int it = 0; it < 3; it++) {
        hipMemsetAsync(s, 0, 512 * sizeof(float), stream);
        route_s<<<dim3(16, 25), 256, 0, stream>>>(pri, lg, s);
        squash_v<<<1, 512, 0, stream>>>(s, v);
        if (it < 2) route_logit<<<2000, 256, 0, stream>>>(pri, v, lg);
    }

    // classes (output 0) + masked decoder input
    classes_mask<<<1, 512, 0, stream>>>(v, out, d0);

    // decoder
    dec_small<32><<<2, 256, 0, stream>>>(d0, dec_w1, dec_b1, d1, 512);
    dec_small<512><<<8, 256, 0, stream>>>(d1, dec_w2, dec_b2, d2, 2048);

    hipMemsetAsync(d3, 0, (size_t)16 * 10240 * sizeof(float), stream);
    dec_split<<<dim3(10, 16), 256, 16 * 128 * sizeof(float), stream>>>(d2, dec_w3, d3, 10240, 2048, 128);
    bias_act<<<(16 * 10240 + 255) / 256, 256, 0, stream>>>(d3, dec_b3, d3, 10240, 16 * 10240, 0);

    hipMemsetAsync(d4, 0, (size_t)16 * 27000 * sizeof(float), stream);
    dec_split<<<dim3(27, 16), 256, 16 * 640 * sizeof(float), stream>>>(d3, dec_w4, d4, 27000, 10240, 640);
    bias_act<<<(16 * 27000 + 255) / 256, 256, 0, stream>>>(d4, dec_b4, out + 32, 27000, 16 * 27000, 1);
}

// Round 4
// 2050.209 us; speedup vs baseline: 3.1681x; 3.1681x over previous
//
#include <hip/hip_runtime.h>
#include <hip/hip_bf16.h>

// ---------------- problem constants ----------------
#define NB   16          // batch
#define C1   128         // conv1 out channels
#define XS   29          // input spatial
#define HS   27          // h spatial (29-3+1)
#define HSP  19683       // 27^3
#define PS   10          // pcaps out spatial
#define PSP  1000        // 10^3
#define RR   16000       // R = 16*1000
#define NCAP 2
#define KTAP 729         // 9^3
#define HTOT 40310784L   // NB*HSP*C1

// ---------------- workspace layout (float units) ----------------
#define OFF_WT   0UL                       // w2 bf16: 729*128*128 ushort (fits 11.9M floats)
#define OFF_H    11943936UL                // h bf16: 40,310,784 ushort (fits region)
#define OFF_P    52254720UL                // 2,048,000   p[b][sp][oc] fp32
#define OFF_U    54302720UL                // 2,048,000   u[b][r][8]
#define OFF_PRI  56350720UL                // 8,192,000   priors[b][c][r][16]
#define OFF_LOG  64542720UL                // 512,000     logits[b][c][r]
#define OFF_S    65054720UL
#define OFF_V    65055232UL
#define OFF_D0   65055744UL
#define OFF_D1   65056256UL
#define OFF_D2   65064448UL
#define OFF_D3   65097216UL
#define OFF_D4   65261056UL

typedef __attribute__((ext_vector_type(8))) short bf16x8;
typedef __attribute__((ext_vector_type(4))) float f32x4;

#define GL2LDS16(g, l) __builtin_amdgcn_global_load_lds( \
    (const __attribute__((address_space(1))) void*)(g), \
    (__attribute__((address_space(3))) void*)(l), 16, 0, 0)

// ============ prep: w2[tap][oc][ic] (bf16) = pcaps_w[oc][ic][tap] (fp32) ============
// 32x32 (ic,tap) tile transpose per oc. grid (23 tapT, 4 icT, 128 oc), block 256 = 32x8
__global__ void prep_w2(const float* __restrict__ w, __hip_bfloat16* __restrict__ w2) {
    __shared__ float tile[32][33];
    int tap0 = blockIdx.x * 32;
    int ic0  = blockIdx.y * 32;
    int oc   = blockIdx.z;
    int tx = threadIdx.x & 31, ty = threadIdx.x >> 5;
    #pragma unroll
    for (int j = 0; j < 32; j += 8) {
        int tap = tap0 + tx, ic = ic0 + ty + j;
        if (tap < KTAP) tile[ty + j][tx] = w[(size_t)oc * 93312 + (size_t)ic * KTAP + tap];
    }
    __syncthreads();
    #pragma unroll
    for (int j = 0; j < 32; j += 8) {
        int tap = tap0 + ty + j, ic = ic0 + tx;
        if (tap < KTAP)
            w2[((size_t)tap * 128 + oc) * 128 + ic] = __float2bfloat16(tile[tx][ty + j]);
    }
}

// ============ conv1 3x3x3 stride1 + bias + relu -> h bf16 channel-last ============
__global__ void conv1_relu(const float* __restrict__ x, const float* __restrict__ w,
                           const float* __restrict__ bias, __hip_bfloat16* __restrict__ h) {
    __shared__ float wl[27][128];
    int t = threadIdx.x;
    for (int i = t; i < 27 * 128; i += 256) wl[i % 27][i / 27] = w[i];
    __syncthreads();
    long gid = (long)blockIdx.x * 256 + t;     // over NB*HSP*C1, grid exact
    int c   = (int)(gid & 127);
    int spz = (int)(gid >> 7);
    int b = spz / HSP, sp = spz % HSP;
    int z = sp / 729, y = (sp / 27) % 27, xx = sp % 27;
    const float* xb = x + (size_t)b * (XS * XS * XS);
    float acc = bias[c];
    #pragma unroll
    for (int dz = 0; dz < 3; dz++)
        #pragma unroll
        for (int dy = 0; dy < 3; dy++)
            #pragma unroll
            for (int dx = 0; dx < 3; dx++)
                acc += xb[((z + dz) * XS + (y + dy)) * XS + (xx + dx)] * wl[(dz * 3 + dy) * 3 + dx][c];
    h[gid] = __float2bfloat16(fmaxf(acc, 0.f));
}

// ============ pcaps implicit-im2col MFMA GEMM (bf16 in, fp32 acc) ============
// M=16000 (b,spatial), N=128 (oc), K=93312 (tap,ic). 128x128 tile, BK=64,
// K-split x8 over taps, atomicAdd fp32 epilogue. m97 2-barrier structure.
__global__ __launch_bounds__(256) void pcaps_mfma(const ushort* __restrict__ hu,
                                                  const ushort* __restrict__ wu,
                                                  float* __restrict__ p) {
    __shared__ __align__(16) ushort As[128 * 64];   // As[m][k]  k contiguous
    __shared__ __align__(16) ushort Bs[128 * 64];   // Bs[n][k]  k contiguous (B^T)
    int t = threadIdx.x;
    int m0 = blockIdx.x * 128;
    int tap_begin = blockIdx.y * 92;
    int tap_end   = min(KTAP, tap_begin + 92);

    // staging addresses: 4 passes x 256 thr x 16B per tile
    int arow[4], brow[4];
    #pragma unroll
    for (int q = 0; q < 4; q++) {
        int idx = q * 256 + t;
        int row = idx >> 3, seg = idx & 7;          // row: 0..127, seg: 8x16B per 64-elem row
        int m = m0 + row;
        int b = m / PSP, sp = m % PSP;
        int oz = sp / 100, oy = (sp / 10) % 10, ox = sp % 10;
        arow[q] = (((b * HS + 2 * oz) * HS + 2 * oy) * HS + 2 * ox) * 128 + seg * 8;
        brow[q] = row * 128 + seg * 8;              // within one tap's w2[tap][oc][ic] block
    }

    int lane = t & 63, wave = t >> 6;
    int wr = wave >> 1, wc = wave & 1;              // 2x2 waves, each 64x64 output
    int l15 = lane & 15, kq = lane >> 4;            // frag row/col + k-chunk

    f32x4 acc[4][4];
    #pragma unroll
    for (int i = 0; i < 4; i++)
        #pragma unroll
        for (int j = 0; j < 4; j++) acc[i][j] = (f32x4)0.f;

    for (int tap = tap_begin; tap < tap_end; ++tap) {
        int dz = tap / 81, dy = (tap / 9) % 9, dx = tap % 9;
        int tapoff = ((dz * HS + dy) * HS + dx) * 128;
        const ushort* wtap = wu + ((size_t)tap << 14);   // tap*128*128
        #pragma unroll
        for (int ich = 0; ich < 2; ++ich) {              // BK=64: two 64-ic halves
            // stage A-tile (16KB) + B-tile (16KB) via global_load_lds width 16
            #pragma unroll
            for (int q = 0; q < 4; q++) {
                int idx = q * 256 + t;
                GL2LDS16(hu + arow[q] + tapoff + ich * 64, As + idx * 8);
            }
            #pragma unroll
            for (int q = 0; q < 4; q++) {
                int idx = q * 256 + t;
                GL2LDS16(wtap + brow[q] + ich * 64, Bs + idx * 8);
            }
            __syncthreads();
            #pragma unroll
            for (int ks = 0; ks < 2; ++ks) {
                bf16x8 av[4], bv[4];
                #pragma unroll
                for (int i = 0; i < 4; i++)
                    av[i] = *(const bf16x8*)&As[(wr * 64 + i * 16 + l15) * 64 + ks * 32 + kq * 8];
                #pragma unroll
                for (int j = 0; j < 4; j++)
                    bv[j] = *(const bf16x8*)&Bs[(wc * 64 + j * 16 + l15) * 64 + ks * 32 + kq * 8];
                #pragma unroll
                for (int i = 0; i < 4; i++)
                    #pragma unroll
                    for (int j = 0; j < 4; j++)
                        acc[i][j] = __builtin_amdgcn_mfma_f32_16x16x32_bf16(av[i], bv[j], acc[i][j], 0, 0, 0);
            }
            __syncthreads();
        }
    }

    // epilogue: C/D layout col=lane&15, row=(lane>>4)*4+reg  (m89-verified)
    #pragma unroll
    for (int i = 0; i < 4; i++) {
        int mbase = m0 + wr * 64 + i * 16 + kq * 4;
        #pragma unroll
        for (int j = 0; j < 4; j++) {
            int n = wc * 64 + j * 16 + l15;
            #pragma unroll
            for (int r = 0; r < 4; r++)
                atomicAdd(&p[(size_t)(mbase + r) * 128 + n], acc[i][j][r]);
        }
    }
}

// ============ squash over capsule-dim 8 -> u[b][r][8] ============
__global__ void squash_u(const float* __restrict__ p, const float* __restrict__ pb,
                         float* __restrict__ u) {
    int gid = blockIdx.x * 256 + threadIdx.x;      // NB*RR = 256000, exact grid
    int b = gid / RR, r = gid % RR;
    int s = r % PSP, rq = r / PSP;
    float vals[8]; float ss = 0.f;
    #pragma unroll
    for (int i = 0; i < 8; i++) {
        int ch = i * 16 + rq;
        float pv = p[((size_t)b * PSP + s) * 128 + ch] + pb[ch];
        vals[i] = pv; ss += pv * pv;
    }
    float n = sqrtf(ss);
    float scale = ss / (1.f + ss) / (n + 1e-8f);
    #pragma unroll
    for (int i = 0; i < 8; i++) u[(size_t)gid * 8 + i] = vals[i] * scale;
}

// ============ priors[b][c][r][16] = sum_i u[b][r][i] * rw[c][r][i][16] ============
__global__ void priors_k(const float* __restrict__ u, const float* __restrict__ rw,
                         float* __restrict__ pri) {
    __shared__ float wl[16][132];
    int bx = blockIdx.x; int c = bx / 1000; int r0 = (bx % 1000) * 16;
    int t = threadIdx.x;
    const float4* src = (const float4*)(rw + ((size_t)c * RR + r0) * 128);
    #pragma unroll
    for (int q = 0; q < 8; q++) {
        int idx = q * 256 + t;
        int row = idx >> 5, c4 = idx & 31;
        *(float4*)&wl[row][c4 * 4] = src[idx];
    }
    __syncthreads();
    int bb = t >> 4, rl = t & 15;
    const float* up = u + ((size_t)bb * RR + r0 + rl) * 8;
    float4 u0 = *(const float4*)up, u1 = *(const float4*)(up + 4);
    float uu[8] = {u0.x, u0.y, u0.z, u0.w, u1.x, u1.y, u1.z, u1.w};
    float out[16];
    #pragma unroll
    for (int o = 0; o < 16; o++) out[o] = 0.f;
    #pragma unroll
    for (int i = 0; i < 8; i++)
        #pragma unroll
        for (int o = 0; o < 16; o++) out[o] += uu[i] * wl[rl][i * 16 + o];
    float* dst = pri + ((size_t)(bb * 2 + c) * RR + r0 + rl) * 16;
    #pragma unroll
    for (int q = 0; q < 4; q++)
        *(float4*)&dst[q * 4] = make_float4(out[q*4], out[q*4+1], out[q*4+2], out[q*4+3]);
}

// ============ routing: s[b][c][16] = sum_r softmax_c(logits) * priors ============
__global__ void route_s(const float* __restrict__ pri, const float* __restrict__ lg,
                        float* __restrict__ s) {
    int b = blockIdx.x, chunk = blockIdx.y;
    int t = threadIdx.x, o = t & 15, rl = t >> 4;
    float acc0 = 0.f, acc1 = 0.f;
    for (int j = 0; j < 40; j++) {
        int r = chunk * 640 + j * 16 + rl;
        float l0 = lg[(size_t)(b * 2 + 0) * RR + r];
        float l1 = lg[(size_t)(b * 2 + 1) * RR + r];
        float m = fmaxf(l0, l1);
        float e0 = __expf(l0 - m), e1 = __expf(l1 - m);
        float inv = 1.f / (e0 + e1);
        acc0 += (e0 * inv) * pri[((size_t)(b * 2 + 0) * RR + r) * 16 + o];
        acc1 += (e1 * inv) * pri[((size_t)(b * 2 + 1) * RR + r) * 16 + o];
    }
    __shared__ float red[2][16][17];
    red[0][rl][o] = acc0; red[1][rl][o] = acc1;
    __syncthreads();
    for (int step = 8; step >= 1; step >>= 1) {
        if (rl < step) {
            red[0][rl][o] += red[0][rl + step][o];
            red[1][rl][o] += red[1][rl + step][o];
        }
        __syncthreads();
    }
    if (rl == 0) {
        atomicAdd(&s[(b * 2 + 0) * 16 + o], red[0][0][o]);
        atomicAdd(&s[(b * 2 + 1) * 16 + o], red[1][0][o]);
    }
}

__global__ void squash_v(const float* __restrict__ s, float* __restrict__ v) {
    int t = threadIdx.x;            // 512 = 32 bc * 16 o
    int bc = t >> 4, o = t & 15;
    float ss = 0.f;
    #pragma unroll
    for (int i = 0; i < 16; i++) { float x = s[bc * 16 + i]; ss += x * x; }
    float n = sqrtf(ss);
    float sc = ss / (1.f + ss) / (n + 1e-8f);
    v[bc * 16 + o] = s[bc * 16 + o] * sc;
}

__global__ void route_logit(const float* __restrict__ pri, const float* __restrict__ v,
                            float* __restrict__ lg) {
    int gid = blockIdx.x * 256 + threadIdx.x;    // 512000 exact
    int bc = gid / RR;
    const float* pp = pri + (size_t)gid * 16;
    float dot = 0.f;
    #pragma unroll
    for (int o = 0; o < 16; o++) dot += pp[o] * v[bc * 16 + o];
    lg[gid] += dot;
}

// ============ classes + argmax mask -> d0[16][32], classes -> d_out[0:32] ============
__global__ void classes_mask(const float* __restrict__ v, float* __restrict__ out,
                             float* __restrict__ d0) {
    __shared__ float cls[32];
    int t = threadIdx.x;
    if (t < 32) {
        float ss = 0.f;
        #pragma unroll
        for (int i = 0; i < 16; i++) { float x = v[t * 16 + i]; ss += x * x; }
        float n = sqrtf(ss);
        cls[t] = n; out[t] = n;
    }
    __syncthreads();
    int b = t >> 5, k = t & 31, c = k >> 4;
    int win = (cls[b * 2 + 1] > cls[b * 2 + 0]) ? 1 : 0;
    d0[t] = (c == win) ? v[b * 32 + k] : 0.f;
}

// ============ decoder small layers (full-K, bias+relu) ============
template<int K>
__global__ void dec_small(const float* __restrict__ din, const float* __restrict__ W,
                          const float* __restrict__ bias, float* __restrict__ dout, int N) {
    __shared__ float dl[16 * K];
    int t = threadIdx.x;
    for (int i = t; i < 16 * K; i += 256) dl[i] = din[i];
    __syncthreads();
    int n = blockIdx.x * 256 + t;
    if (n >= N) return;
    float acc[16];
    float bv = bias[n];
    #pragma unroll
    for (int b = 0; b < 16; b++) acc[b] = bv;
    for (int k = 0; k < K; k++) {
        float w = W[(size_t)k * N + n];
        #pragma unroll
        for (int b = 0; b < 16; b++) acc[b] += dl[b * K + k] * w;
    }
    #pragma unroll
    for (int b = 0; b < 16; b++) dout[(size_t)b * N + n] = fmaxf(acc[b], 0.f);
}

// ============ decoder big layers: K-split partial GEMM (atomic) ============
__global__ void dec_split(const float* __restrict__ din, const float* __restrict__ W,
                          float* __restrict__ part, int N, int K, int KC) {
    extern __shared__ float dl[];
    int t = threadIdx.x;
    int k0 = blockIdx.y * KC;
    for (int i = t; i < 16 * KC; i += 256) {
        int b = i / KC, kk = i % KC;
        dl[i] = din[(size_t)b * K + k0 + kk];
    }
    __syncthreads();
    int n = blockIdx.x * 1024 + t;
    bool g0 = n < N, g1 = n + 256 < N, g2 = n + 512 < N, g3 = n + 768 < N;
    float acc[16][4];
    #pragma unroll
    for (int b = 0; b < 16; b++)
        #pragma unroll
        for (int j = 0; j < 4; j++) acc[b][j] = 0.f;
    const float* Wp = W + (size_t)k0 * N + n;
    for (int kk = 0; kk < KC; kk++) {
        float w0 = g0 ? Wp[0]   : 0.f;
        float w1 = g1 ? Wp[256] : 0.f;
        float w2 = g2 ? Wp[512] : 0.f;
        float w3 = g3 ? Wp[768] : 0.f;
        Wp += N;
        #pragma unroll
        for (int b = 0; b < 16; b++) {
            float dv = dl[b * KC + kk];
            acc[b][0] += dv * w0; acc[b][1] += dv * w1;
            acc[b][2] += dv * w2; acc[b][3] += dv * w3;
        }
    }
    #pragma unroll
    for (int j = 0; j < 4; j++)
        if (n + j * 256 < N)
            #pragma unroll
            for (int b = 0; b < 16; b++)
                atomicAdd(&part[(size_t)b * N + n + j * 256], acc[b][j]);
}

__global__ void bias_act(const float* __restrict__ part, const float* __restrict__ bias,
                         float* __restrict__ out, int N, int total, int sigm) {
    int gid = blockIdx.x * 256 + threadIdx.x;
    if (gid >= total) return;
    int n = gid % N;
    float x = part[gid] + bias[n];
    out[gid] = sigm ? (1.f / (1.f + __expf(-x))) : fmaxf(x, 0.f);
}

// ================================================================
extern "C" void kernel_launch(void* const* d_in, const int* in_sizes, int n_in,
                              void* d_out, int out_size, void* d_ws, size_t ws_size,
                              hipStream_t stream) {
    const float* x        = (const float*)d_in[0];
    const float* conv1_w  = (const float*)d_in[1];
    const float* conv1_b  = (const float*)d_in[2];
    const float* pcaps_w  = (const float*)d_in[3];
    const float* pcaps_b  = (const float*)d_in[4];
    const float* route_w  = (const float*)d_in[5];
    const float* dec_w1   = (const float*)d_in[6];
    const float* dec_b1   = (const float*)d_in[7];
    const float* dec_w2   = (const float*)d_in[8];
    const float* dec_b2   = (const float*)d_in[9];
    const float* dec_w3   = (const float*)d_in[10];
    const float* dec_b3   = (const float*)d_in[11];
    const float* dec_w4   = (const float*)d_in[12];
    const float* dec_b4   = (const float*)d_in[13];
    float* out = (float*)d_out;

    float* ws = (float*)d_ws;
    __hip_bfloat16* w2 = (__hip_bfloat16*)(ws + OFF_WT);
    __hip_bfloat16* h  = (__hip_bfloat16*)(ws + OFF_H);
    float* p    = ws + OFF_P;
    float* u    = ws + OFF_U;
    float* pri  = ws + OFF_PRI;
    float* lg   = ws + OFF_LOG;
    float* s    = ws + OFF_S;
    float* v    = ws + OFF_V;
    float* d0   = ws + OFF_D0;
    float* d1   = ws + OFF_D1;
    float* d2   = ws + OFF_D2;
    float* d3   = ws + OFF_D3;
    float* d4   = ws + OFF_D4;

    // prep + conv1 (h in bf16 channel-last)
    prep_w2<<<dim3(23, 4, 128), 256, 0, stream>>>(pcaps_w, w2);
    conv1_relu<<<(int)(HTOT / 256), 256, 0, stream>>>(x, conv1_w, conv1_b, h);

    // pcaps conv: bf16 MFMA implicit GEMM, K-split x8, atomic fp32 accumulate
    hipMemsetAsync(p, 0, (size_t)NB * PSP * 128 * sizeof(float), stream);
    pcaps_mfma<<<dim3(125, 8), 256, 0, stream>>>((const ushort*)h, (const ushort*)w2, p);

    // squash -> u ; priors einsum
    squash_u<<<1000, 256, 0, stream>>>(p, pcaps_b, u);
    priors_k<<<2000, 256, 0, stream>>>(u, route_w, pri);

    // dynamic routing, 3 iterations
    hipMemsetAsync(lg, 0, (size_t)NB * NCAP * RR * sizeof(float), stream);
    for (int it = 0; it < 3; it++) {
        hipMemsetAsync(s, 0, 512 * sizeof(float), stream);
        route_s<<<dim3(16, 25), 256, 0, stream>>>(pri, lg, s);
        squash_v<<<1, 512, 0, stream>>>(s, v);
        if (it < 2) route_logit<<<2000, 256, 0, stream>>>(pri, v, lg);
    }

    // classes (output 0) + masked decoder input
    classes_mask<<<1, 512, 0, stream>>>(v, out, d0);

    // decoder
    dec_small<32><<<2, 256, 0, stream>>>(d0, dec_w1, dec_b1, d1, 512);
    dec_small<512><<<8, 256, 0, stream>>>(d1, dec_w2, dec_b2, d2, 2048);

    hipMemsetAsync(d3, 0, (size_t)16 * 10240 * sizeof(float), stream);
    dec_split<<<dim3(10, 16), 256, 16 * 128 * sizeof(float), stream>>>(d2, dec_w3, d3, 10240, 2048, 128);
    bias_act<<<(16 * 10240 + 255) / 256, 256, 0, stream>>>(d3, dec_b3, d3, 10240, 16 * 10240, 0);

    hipMemsetAsync(d4, 0, (size_t)16 * 27000 * sizeof(float), stream);
    dec_split<<<dim3(27, 16), 256, 16 * 640 * sizeof(float), stream>>>(d3, dec_w4, d4, 27000, 10240, 640);
    bias_act<<<(16 * 27000 + 255) / 256, 256, 0, stream>>>(d4, dec_b4, out + 32, 27000, 16 * 27000, 1);
}

// Round 6
// 1560.577 us; speedup vs baseline: 4.1621x; 1.3138x over previous
//
#include <hip/hip_runtime.h>
#include <hip/hip_bf16.h>

// ---------------- problem constants ----------------
#define NB   16          // batch
#define C1   128         // conv1 out channels
#define XS   29          // input spatial
#define HS   27          // h spatial (29-3+1)
#define HSP  19683       // 27^3
#define PS   10          // pcaps out spatial
#define PSP  1000        // 10^3
#define RR   16000       // R = 16*1000
#define NCAP 2
#define KTAP 729         // 9^3
#define HTOT 40310784L   // NB*HSP*C1
#define SPTOT 314928     // NB*HSP

// ---------------- workspace layout (float units) ----------------
#define OFF_WT   0UL                       // w2 bf16: 729*128*128 ushort (fits 11.9M floats)
#define OFF_H    11943936UL                // h bf16: 40,310,784 ushort (fits region)
#define OFF_P    52254720UL                // 2,048,000   p[b][sp][oc] fp32
#define OFF_U    54302720UL                // 2,048,000   u[b][r][8]
#define OFF_PRI  56350720UL                // 8,192,000   priors[b][c][r][16]
#define OFF_LOG  64542720UL                // 512,000     logits[b][c][r]
#define OFF_S    65054720UL
#define OFF_V    65055232UL
#define OFF_D0   65055744UL
#define OFF_D1   65056256UL
#define OFF_D2   65064448UL
#define OFF_D3   65097216UL
#define OFF_D4   65261056UL

typedef __attribute__((ext_vector_type(8))) short bf16x8;
typedef __attribute__((ext_vector_type(4))) float f32x4;

#define GL2LDS16(g, l) __builtin_amdgcn_global_load_lds( \
    (const __attribute__((address_space(1))) void*)(g), \
    (__attribute__((address_space(3))) void*)(l), 16, 0, 0)

// ============ prep: w2[tap][oc][ic] (bf16) = pcaps_w[oc][ic][tap] (fp32) ============
// 32x32 (ic,tap) tile transpose per oc. grid (23 tapT, 4 icT, 128 oc), block 256 = 32x8
__global__ void prep_w2(const float* __restrict__ w, __hip_bfloat16* __restrict__ w2) {
    __shared__ float tile[32][33];
    int tap0 = blockIdx.x * 32;
    int ic0  = blockIdx.y * 32;
    int oc   = blockIdx.z;
    int tx = threadIdx.x & 31, ty = threadIdx.x >> 5;
    #pragma unroll
    for (int j = 0; j < 32; j += 8) {
        int tap = tap0 + tx, ic = ic0 + ty + j;
        if (tap < KTAP) tile[ty + j][tx] = w[(size_t)oc * 93312 + (size_t)ic * KTAP + tap];
    }
    __syncthreads();
    #pragma unroll
    for (int j = 0; j < 32; j += 8) {
        int tap = tap0 + ty + j, ic = ic0 + tx;
        if (tap < KTAP)
            w2[((size_t)tap * 128 + oc) * 128 + ic] = __float2bfloat16(tile[tx][ty + j]);
    }
}

// ============ conv1 3x3x3 stride1 + bias + relu -> h bf16 channel-last ============
// Register-resident weights (27/thread, channel fixed), no LDS. 32 sp/block,
// 16 sp/thread; x-loads are wave-uniform (one line broadcast), h-writes coalesced.
__global__ __launch_bounds__(256) void conv1_relu(const float* __restrict__ x,
                                                  const float* __restrict__ w,
                                                  const float* __restrict__ bias,
                                                  __hip_bfloat16* __restrict__ h) {
    int t = threadIdx.x;
    int c = t & 127;
    float wr[27];
    #pragma unroll
    for (int k = 0; k < 27; k++) wr[k] = w[c * 27 + k];
    float bv = bias[c];
    int sp_base = blockIdx.x * 32 + (t >> 7);
    #pragma unroll 4
    for (int i = 0; i < 16; i++) {
        int spg = sp_base + i * 2;
        if (spg >= SPTOT) return;
        int b = spg / HSP, sp = spg % HSP;
        int z = sp / 729, y = (sp / 27) % 27, xx = sp % 27;
        const float* xb = x + (size_t)b * (XS * XS * XS) + ((size_t)z * XS + y) * XS + xx;
        float xv[27];
        #pragma unroll
        for (int dz = 0; dz < 3; dz++)
            #pragma unroll
            for (int dy = 0; dy < 3; dy++)
                #pragma unroll
                for (int dx = 0; dx < 3; dx++)
                    xv[(dz * 3 + dy) * 3 + dx] = xb[((size_t)dz * XS + dy) * XS + dx];
        float acc = bv;
        #pragma unroll
        for (int k = 0; k < 27; k++) acc = fmaf(xv[k], wr[k], acc);
        h[(size_t)spg * 128 + c] = __float2bfloat16(fmaxf(acc, 0.f));
    }
}

// ============ pcaps implicit-im2col MFMA GEMM (bf16 in, fp32 acc) ============
// M=16000 (b,spatial), N=128 (oc), K=93312 (tap,ic). 128x128 tile, BK=64,
// K-split x8 over taps, atomicAdd fp32 epilogue. m97 2-barrier structure.
__global__ __launch_bounds__(256) void pcaps_mfma(const ushort* __restrict__ hu,
                                                  const ushort* __restrict__ wu,
                                                  float* __restrict__ p) {
    __shared__ __align__(16) ushort As[128 * 64];   // As[m][k]  k contiguous
    __shared__ __align__(16) ushort Bs[128 * 64];   // Bs[n][k]  k contiguous (B^T)
    int t = threadIdx.x;
    int m0 = blockIdx.x * 128;
    int tap_begin = blockIdx.y * 92;
    int tap_end   = min(KTAP, tap_begin + 92);

    // staging addresses: 4 passes x 256 thr x 16B per tile
    int arow[4], brow[4];
    #pragma unroll
    for (int q = 0; q < 4; q++) {
        int idx = q * 256 + t;
        int row = idx >> 3, seg = idx & 7;          // row: 0..127, seg: 8x16B per 64-elem row
        int m = m0 + row;
        int b = m / PSP, sp = m % PSP;
        int oz = sp / 100, oy = (sp / 10) % 10, ox = sp % 10;
        arow[q] = (((b * HS + 2 * oz) * HS + 2 * oy) * HS + 2 * ox) * 128 + seg * 8;
        brow[q] = row * 128 + seg * 8;              // within one tap's w2[tap][oc][ic] block
    }

    int lane = t & 63, wave = t >> 6;
    int wr = wave >> 1, wc = wave & 1;              // 2x2 waves, each 64x64 output
    int l15 = lane & 15, kq = lane >> 4;            // frag row/col + k-chunk

    f32x4 acc[4][4];
    #pragma unroll
    for (int i = 0; i < 4; i++)
        #pragma unroll
        for (int j = 0; j < 4; j++) acc[i][j] = (f32x4)0.f;

    for (int tap = tap_begin; tap < tap_end; ++tap) {
        int dz = tap / 81, dy = (tap / 9) % 9, dx = tap % 9;
        int tapoff = ((dz * HS + dy) * HS + dx) * 128;
        const ushort* wtap = wu + ((size_t)tap << 14);   // tap*128*128
        #pragma unroll
        for (int ich = 0; ich < 2; ++ich) {              // BK=64: two 64-ic halves
            // stage A-tile (16KB) + B-tile (16KB) via global_load_lds width 16
            #pragma unroll
            for (int q = 0; q < 4; q++) {
                int idx = q * 256 + t;
                GL2LDS16(hu + arow[q] + tapoff + ich * 64, As + idx * 8);
            }
            #pragma unroll
            for (int q = 0; q < 4; q++) {
                int idx = q * 256 + t;
                GL2LDS16(wtap + brow[q] + ich * 64, Bs + idx * 8);
            }
            __syncthreads();
            #pragma unroll
            for (int ks = 0; ks < 2; ++ks) {
                bf16x8 av[4], bv[4];
                #pragma unroll
                for (int i = 0; i < 4; i++)
                    av[i] = *(const bf16x8*)&As[(wr * 64 + i * 16 + l15) * 64 + ks * 32 + kq * 8];
                #pragma unroll
                for (int j = 0; j < 4; j++)
                    bv[j] = *(const bf16x8*)&Bs[(wc * 64 + j * 16 + l15) * 64 + ks * 32 + kq * 8];
                #pragma unroll
                for (int i = 0; i < 4; i++)
                    #pragma unroll
                    for (int j = 0; j < 4; j++)
                        acc[i][j] = __builtin_amdgcn_mfma_f32_16x16x32_bf16(av[i], bv[j], acc[i][j], 0, 0, 0);
            }
            __syncthreads();
        }
    }

    // epilogue: C/D layout col=lane&15, row=(lane>>4)*4+reg  (m89-verified)
    #pragma unroll
    for (int i = 0; i < 4; i++) {
        int mbase = m0 + wr * 64 + i * 16 + kq * 4;
        #pragma unroll
        for (int j = 0; j < 4; j++) {
            int n = wc * 64 + j * 16 + l15;
            #pragma unroll
            for (int r = 0; r < 4; r++)
                atomicAdd(&p[(size_t)(mbase + r) * 128 + n], acc[i][j][r]);
        }
    }
}

// ============ squash over capsule-dim 8 -> u[b][r][8] ============
__global__ void squash_u(const float* __restrict__ p, const float* __restrict__ pb,
                         float* __restrict__ u) {
    int gid = blockIdx.x * 256 + threadIdx.x;      // NB*RR = 256000, exact grid
    int b = gid / RR, r = gid % RR;
    int s = r % PSP, rq = r / PSP;
    float vals[8]; float ss = 0.f;
    #pragma unroll
    for (int i = 0; i < 8; i++) {
        int ch = i * 16 + rq;
        float pv = p[((size_t)b * PSP + s) * 128 + ch] + pb[ch];
        vals[i] = pv; ss += pv * pv;
    }
    float n = sqrtf(ss);
    float scale = ss / (1.f + ss) / (n + 1e-8f);
    #pragma unroll
    for (int i = 0; i < 8; i++) u[(size_t)gid * 8 + i] = vals[i] * scale;
}

// ============ priors[b][c][r][16] = sum_i u[b][r][i] * rw[c][r][i][16] ============
__global__ void priors_k(const float* __restrict__ u, const float* __restrict__ rw,
                         float* __restrict__ pri) {
    __shared__ float wl[16][132];
    int bx = blockIdx.x; int c = bx / 1000; int r0 = (bx % 1000) * 16;
    int t = threadIdx.x;
    const float4* src = (const float4*)(rw + ((size_t)c * RR + r0) * 128);
    #pragma unroll
    for (int q = 0; q < 8; q++) {
        int idx = q * 256 + t;
        int row = idx >> 5, c4 = idx & 31;
        *(float4*)&wl[row][c4 * 4] = src[idx];
    }
    __syncthreads();
    int bb = t >> 4, rl = t & 15;
    const float* up = u + ((size_t)bb * RR + r0 + rl) * 8;
    float4 u0 = *(const float4*)up, u1 = *(const float4*)(up + 4);
    float uu[8] = {u0.x, u0.y, u0.z, u0.w, u1.x, u1.y, u1.z, u1.w};
    float out[16];
    #pragma unroll
    for (int o = 0; o < 16; o++) out[o] = 0.f;
    #pragma unroll
    for (int i = 0; i < 8; i++)
        #pragma unroll
        for (int o = 0; o < 16; o++) out[o] += uu[i] * wl[rl][i * 16 + o];
    float* dst = pri + ((size_t)(bb * 2 + c) * RR + r0 + rl) * 16;
    #pragma unroll
    for (int q = 0; q < 4; q++)
        *(float4*)&dst[q * 4] = make_float4(out[q*4], out[q*4+1], out[q*4+2], out[q*4+3]);
}

// ============ routing: s[b][c][16] = sum_r softmax_c(logits) * priors ============
__global__ void route_s(const float* __restrict__ pri, const float* __restrict__ lg,
                        float* __restrict__ s) {
    int b = blockIdx.x, chunk = blockIdx.y;
    int t = threadIdx.x, o = t & 15, rl = t >> 4;
    float acc0 = 0.f, acc1 = 0.f;
    for (int j = 0; j < 40; j++) {
        int r = chunk * 640 + j * 16 + rl;
        float l0 = lg[(size_t)(b * 2 + 0) * RR + r];
        float l1 = lg[(size_t)(b * 2 + 1) * RR + r];
        float m = fmaxf(l0, l1);
        float e0 = __expf(l0 - m), e1 = __expf(l1 - m);
        float inv = 1.f / (e0 + e1);
        acc0 += (e0 * inv) * pri[((size_t)(b * 2 + 0) * RR + r) * 16 + o];
        acc1 += (e1 * inv) * pri[((size_t)(b * 2 + 1) * RR + r) * 16 + o];
    }
    __shared__ float red[2][16][17];
    red[0][rl][o] = acc0; red[1][rl][o] = acc1;
    __syncthreads();
    for (int step = 8; step >= 1; step >>= 1) {
        if (rl < step) {
            red[0][rl][o] += red[0][rl + step][o];
            red[1][rl][o] += red[1][rl + step][o];
        }
        __syncthreads();
    }
    if (rl == 0) {
        atomicAdd(&s[(b * 2 + 0) * 16 + o], red[0][0][o]);
        atomicAdd(&s[(b * 2 + 1) * 16 + o], red[1][0][o]);
    }
}

__global__ void squash_v(const float* __restrict__ s, float* __restrict__ v) {
    int t = threadIdx.x;            // 512 = 32 bc * 16 o
    int bc = t >> 4, o = t & 15;
    float ss = 0.f;
    #pragma unroll
    for (int i = 0; i < 16; i++) { float x = s[bc * 16 + i]; ss += x * x; }
    float n = sqrtf(ss);
    float sc = ss / (1.f + ss) / (n + 1e-8f);
    v[bc * 16 + o] = s[bc * 16 + o] * sc;
}

__global__ void route_logit(const float* __restrict__ pri, const float* __restrict__ v,
                            float* __restrict__ lg) {
    int gid = blockIdx.x * 256 + threadIdx.x;    // 512000 exact
    int bc = gid / RR;
    const float* pp = pri + (size_t)gid * 16;
    float dot = 0.f;
    #pragma unroll
    for (int o = 0; o < 16; o++) dot += pp[o] * v[bc * 16 + o];
    lg[gid] += dot;
}

// ============ classes + argmax mask -> d0[16][32], classes -> d_out[0:32] ============
__global__ void classes_mask(const float* __restrict__ v, float* __restrict__ out,
                             float* __restrict__ d0) {
    __shared__ float cls[32];
    int t = threadIdx.x;
    if (t < 32) {
        float ss = 0.f;
        #pragma unroll
        for (int i = 0; i < 16; i++) { float x = v[t * 16 + i]; ss += x * x; }
        float n = sqrtf(ss);
        cls[t] = n; out[t] = n;
    }
    __syncthreads();
    int b = t >> 5, k = t & 31, c = k >> 4;
    int win = (cls[b * 2 + 1] > cls[b * 2 + 0]) ? 1 : 0;
    d0[t] = (c == win) ? v[b * 32 + k] : 0.f;
}

// ============ decoder small layers (full-K, bias+relu) ============
template<int K>
__global__ void dec_small(const float* __restrict__ din, const float* __restrict__ W,
                          const float* __restrict__ bias, float* __restrict__ dout, int N) {
    __shared__ float dl[16 * K];
    int t = threadIdx.x;
    for (int i = t; i < 16 * K; i += 256) dl[i] = din[i];
    __syncthreads();
    int n = blockIdx.x * 256 + t;
    if (n >= N) return;
    float acc[16];
    float bv = bias[n];
    #pragma unroll
    for (int b = 0; b < 16; b++) acc[b] = bv;
    for (int k = 0; k < K; k++) {
        float w = W[(size_t)k * N + n];
        #pragma unroll
        for (int b = 0; b < 16; b++) acc[b] += dl[b * K + k] * w;
    }
    #pragma unroll
    for (int b = 0; b < 16; b++) dout[(size_t)b * N + n] = fmaxf(acc[b], 0.f);
}

// ============ decoder big layers: K-split partial GEMM (atomic) ============
__global__ void dec_split(const float* __restrict__ din, const float* __restrict__ W,
                          float* __restrict__ part, int N, int K, int KC) {
    extern __shared__ float dl[];
    int t = threadIdx.x;
    int k0 = blockIdx.y * KC;
    for (int i = t; i < 16 * KC; i += 256) {
        int b = i / KC, kk = i % KC;
        dl[i] = din[(size_t)b * K + k0 + kk];
    }
    __syncthreads();
    int n = blockIdx.x * 1024 + t;
    bool g0 = n < N, g1 = n + 256 < N, g2 = n + 512 < N, g3 = n + 768 < N;
    float acc[16][4];
    #pragma unroll
    for (int b = 0; b < 16; b++)
        #pragma unroll
        for (int j = 0; j < 4; j++) acc[b][j] = 0.f;
    const float* Wp = W + (size_t)k0 * N + n;
    for (int kk = 0; kk < KC; kk++) {
        float w0 = g0 ? Wp[0]   : 0.f;
        float w1 = g1 ? Wp[256] : 0.f;
        float w2 = g2 ? Wp[512] : 0.f;
        float w3 = g3 ? Wp[768] : 0.f;
        Wp += N;
        #pragma unroll
        for (int b = 0; b < 16; b++) {
            float dv = dl[b * KC + kk];
            acc[b][0] += dv * w0; acc[b][1] += dv * w1;
            acc[b][2] += dv * w2; acc[b][3] += dv * w3;
        }
    }
    #pragma unroll
    for (int j = 0; j < 4; j++)
        if (n + j * 256 < N)
            #pragma unroll
            for (int b = 0; b < 16; b++)
                atomicAdd(&part[(size_t)b * N + n + j * 256], acc[b][j]);
}

__global__ void bias_act(const float* __restrict__ part, const float* __restrict__ bias,
                         float* __restrict__ out, int N, int total, int sigm) {
    int gid = blockIdx.x * 256 + threadIdx.x;
    if (gid >= total) return;
    int n = gid % N;
    float x = part[gid] + bias[n];
    out[gid] = sigm ? (1.f / (1.f + __expf(-x))) : fmaxf(x, 0.f);
}

// ================================================================
extern "C" void kernel_launch(void* const* d_in, const int* in_sizes, int n_in,
                              void* d_out, int out_size, void* d_ws, size_t ws_size,
                              hipStream_t stream) {
    const float* x        = (const float*)d_in[0];
    const float* conv1_w  = (const float*)d_in[1];
    const float* conv1_b  = (const float*)d_in[2];
    const float* pcaps_w  = (const float*)d_in[3];
    const float* pcaps_b  = (const float*)d_in[4];
    const float* route_w  = (const float*)d_in[5];
    const float* dec_w1   = (const float*)d_in[6];
    const float* dec_b1   = (const float*)d_in[7];
    const float* dec_w2   = (const float*)d_in[8];
    const float* dec_b2   = (const float*)d_in[9];
    const float* dec_w3   = (const float*)d_in[10];
    const float* dec_b3   = (const float*)d_in[11];
    const float* dec_w4   = (const float*)d_in[12];
    const float* dec_b4   = (const float*)d_in[13];
    float* out = (float*)d_out;

    float* ws = (float*)d_ws;
    __hip_bfloat16* w2 = (__hip_bfloat16*)(ws + OFF_WT);
    __hip_bfloat16* h  = (__hip_bfloat16*)(ws + OFF_H);
    float* p    = ws + OFF_P;
    float* u    = ws + OFF_U;
    float* pri  = ws + OFF_PRI;
    float* lg   = ws + OFF_LOG;
    float* s    = ws + OFF_S;
    float* v    = ws + OFF_V;
    float* d0   = ws + OFF_D0;
    float* d1   = ws + OFF_D1;
    float* d2   = ws + OFF_D2;
    float* d3   = ws + OFF_D3;
    float* d4   = ws + OFF_D4;

    // prep + conv1 (h in bf16 channel-last)
    prep_w2<<<dim3(23, 4, 128), 256, 0, stream>>>(pcaps_w, w2);
    conv1_relu<<<(SPTOT + 31) / 32, 256, 0, stream>>>(x, conv1_w, conv1_b, h);

    // pcaps conv: bf16 MFMA implicit GEMM, K-split x8, atomic fp32 accumulate
    hipMemsetAsync(p, 0, (size_t)NB * PSP * 128 * sizeof(float), stream);
    pcaps_mfma<<<dim3(125, 8), 256, 0, stream>>>((const ushort*)h, (const ushort*)w2, p);

    // squash -> u ; priors einsum
    squash_u<<<1000, 256, 0, stream>>>(p, pcaps_b, u);
    priors_k<<<2000, 256, 0, stream>>>(u, route_w, pri);

    // dynamic routing, 3 iterations
    hipMemsetAsync(lg, 0, (size_t)NB * NCAP * RR * sizeof(float), stream);
    for (int it = 0; it < 3; it++) {
        hipMemsetAsync(s, 0, 512 * sizeof(float), stream);
        route_s<<<dim3(16, 25), 256, 0, stream>>>(pri, lg, s);
        squash_v<<<1, 512, 0, stream>>>(s, v);
        if (it < 2) route_logit<<<2000, 256, 0, stream>>>(pri, v, lg);
    }

    // classes (output 0) + masked decoder input
    classes_mask<<<1, 512, 0, stream>>>(v, out, d0);

    // decoder
    dec_small<32><<<2, 256, 0, stream>>>(d0, dec_w1, dec_b1, d1, 512);
    dec_small<512><<<8, 256, 0, stream>>>(d1, dec_w2, dec_b2, d2, 2048);

    hipMemsetAsync(d3, 0, (size_t)16 * 10240 * sizeof(float), stream);
    dec_split<<<dim3(10, 16), 256, 16 * 128 * sizeof(float), stream>>>(d2, dec_w3, d3, 10240, 2048, 128);
    bias_act<<<(16 * 10240 + 255) / 256, 256, 0, stream>>>(d3, dec_b3, d3, 10240, 16 * 10240, 0);

    hipMemsetAsync(d4, 0, (size_t)16 * 27000 * sizeof(float), stream);
    dec_split<<<dim3(27, 16), 256, 16 * 640 * sizeof(float), stream>>>(d3, dec_w4, d4, 27000, 10240, 640);
    bias_act<<<(16 * 27000 + 255) / 256, 256, 0, stream>>>(d4, dec_b4, out + 32, 27000, 16 * 27000, 1);
}

// Round 7
// 1213.881 us; speedup vs baseline: 5.3508x; 1.2856x over previous
//
#include <hip/hip_runtime.h>
#include <hip/hip_bf16.h>

// ---------------- problem constants ----------------
#define NB   16          // batch
#define C1   128         // conv1 out channels
#define XS   29          // input spatial
#define HS   27          // h spatial (29-3+1)
#define HSP  19683       // 27^3
#define PS   10          // pcaps out spatial
#define PSP  1000        // 10^3
#define RR   16000       // R = 16*1000
#define NCAP 2
#define KTAP 729         // 9^3
#define HTOT 40310784L   // NB*HSP*C1
#define SPTOT 314928     // NB*HSP

// ---------------- workspace layout (float units) ----------------
#define OFF_WT   0UL                       // w2 bf16: 729*128*128 ushort (fits 11.9M floats)
#define OFF_H    11943936UL                // h bf16: 40,310,784 ushort (fits region)
#define OFF_P    52254720UL                // 2,048,000   p[b][sp][oc] fp32 (reduced)
#define OFF_U    54302720UL                // 2,048,000   u[b][r][8]
#define OFF_PRI  56350720UL                // 8,192,000   priors[b][c][r][16]
#define OFF_LOG  64542720UL                // 512,000     logits[b][c][r]
#define OFF_S    65054720UL
#define OFF_V    65055232UL
#define OFF_D0   65055744UL
#define OFF_D1   65056256UL
#define OFF_D2   65064448UL
#define OFF_D3   65097216UL
#define OFF_D4   65261056UL
#define OFF_PP   65693056UL                // pcaps partials: 8*16000*128 = 16,384,000
#define OFF_D3P  82077056UL                // dec3 partials: 16*16*10240 = 2,621,440
#define OFF_D4P  84698496UL                // dec4 partials: 16*16*27000 = 6,912,000
                                           // end = 91,610,496 floats ~= 366 MB

typedef __attribute__((ext_vector_type(8))) short bf16x8;
typedef __attribute__((ext_vector_type(4))) float f32x4;

#define GL2LDS16(g, l) __builtin_amdgcn_global_load_lds( \
    (const __attribute__((address_space(1))) void*)(g), \
    (__attribute__((address_space(3))) void*)(l), 16, 0, 0)

// ============ prep: w2[tap][oc][ic] (bf16) = pcaps_w[oc][ic][tap] (fp32) ============
__global__ void prep_w2(const float* __restrict__ w, __hip_bfloat16* __restrict__ w2) {
    __shared__ float tile[32][33];
    int tap0 = blockIdx.x * 32;
    int ic0  = blockIdx.y * 32;
    int oc   = blockIdx.z;
    int tx = threadIdx.x & 31, ty = threadIdx.x >> 5;
    #pragma unroll
    for (int j = 0; j < 32; j += 8) {
        int tap = tap0 + tx, ic = ic0 + ty + j;
        if (tap < KTAP) tile[ty + j][tx] = w[(size_t)oc * 93312 + (size_t)ic * KTAP + tap];
    }
    __syncthreads();
    #pragma unroll
    for (int j = 0; j < 32; j += 8) {
        int tap = tap0 + ty + j, ic = ic0 + tx;
        if (tap < KTAP)
            w2[((size_t)tap * 128 + oc) * 128 + ic] = __float2bfloat16(tile[tx][ty + j]);
    }
}

// ============ conv1 3x3x3 stride1 + bias + relu -> h bf16 channel-last ============
// Register-resident weights (27/thread), no LDS; wave-uniform x broadcast reads.
__global__ __launch_bounds__(256) void conv1_relu(const float* __restrict__ x,
                                                  const float* __restrict__ w,
                                                  const float* __restrict__ bias,
                                                  __hip_bfloat16* __restrict__ h) {
    int t = threadIdx.x;
    int c = t & 127;
    float wr[27];
    #pragma unroll
    for (int k = 0; k < 27; k++) wr[k] = w[c * 27 + k];
    float bv = bias[c];
    int sp_base = blockIdx.x * 32 + (t >> 7);
    #pragma unroll 4
    for (int i = 0; i < 16; i++) {
        int spg = sp_base + i * 2;
        if (spg >= SPTOT) return;
        int b = spg / HSP, sp = spg % HSP;
        int z = sp / 729, y = (sp / 27) % 27, xx = sp % 27;
        const float* xb = x + (size_t)b * (XS * XS * XS) + ((size_t)z * XS + y) * XS + xx;
        float xv[27];
        #pragma unroll
        for (int dz = 0; dz < 3; dz++)
            #pragma unroll
            for (int dy = 0; dy < 3; dy++)
                #pragma unroll
                for (int dx = 0; dx < 3; dx++)
                    xv[(dz * 3 + dy) * 3 + dx] = xb[((size_t)dz * XS + dy) * XS + dx];
        float acc = bv;
        #pragma unroll
        for (int k = 0; k < 27; k++) acc = fmaf(xv[k], wr[k], acc);
        h[(size_t)spg * 128 + c] = __float2bfloat16(fmaxf(acc, 0.f));
    }
}

// ============ pcaps implicit-im2col MFMA GEMM (bf16 in, fp32 acc) ============
// 256x128 tile, 8 waves (4Mx2N, each 64x64), BK=64, K-split x8 over taps.
// tap_group = bid&7 (XCD-pinned w2 slice); atomic-free partial output pp[g][m][n].
__global__ __launch_bounds__(512) void pcaps_mfma(const ushort* __restrict__ hu,
                                                  const ushort* __restrict__ wu,
                                                  float* __restrict__ pp) {
    __shared__ __align__(16) ushort As[256 * 64];   // 32KB, As[m][k] k-contiguous
    __shared__ __align__(16) ushort Bs[128 * 64];   // 16KB, Bs[n][k] k-contiguous
    int t = threadIdx.x;
    int bid = blockIdx.x;
    int g = bid & 7;                 // tap group -> same-XCD for consecutive ids
    int mtile = bid >> 3;            // 0..62
    int m0 = mtile * 256;
    int tap_begin = g * 92;
    int tap_end   = min(KTAP, tap_begin + 92);

    // A staging: 2048 segs of 16B, 4 per thread
    int arow[4];
    #pragma unroll
    for (int q = 0; q < 4; q++) {
        int idx = q * 512 + t;
        int row = idx >> 3, seg = idx & 7;
        int m = m0 + row; if (m > 15999) m = 15999;      // tail clamp (stage dup, store guarded)
        int b = m / PSP, sp = m % PSP;
        int oz = sp / 100, oy = (sp / 10) % 10, ox = sp % 10;
        arow[q] = (((b * HS + 2 * oz) * HS + 2 * oy) * HS + 2 * ox) * 128 + seg * 8;
    }
    // B staging: 1024 segs, 2 per thread
    int brow[2];
    #pragma unroll
    for (int q = 0; q < 2; q++) {
        int idx = q * 512 + t;
        brow[q] = (idx >> 3) * 128 + (idx & 7) * 8;
    }

    int lane = t & 63, wave = t >> 6;
    int wr = wave >> 1, wc = wave & 1;              // 4(M) x 2(N) waves, each 64x64
    int l15 = lane & 15, kq = lane >> 4;

    f32x4 acc[4][4];
    #pragma unroll
    for (int i = 0; i < 4; i++)
        #pragma unroll
        for (int j = 0; j < 4; j++) acc[i][j] = (f32x4)0.f;

    for (int tap = tap_begin; tap < tap_end; ++tap) {
        int dz = tap / 81, dy = (tap / 9) % 9, dx = tap % 9;
        int tapoff = ((dz * HS + dy) * HS + dx) * 128;
        const ushort* wtap = wu + ((size_t)tap << 14);   // tap*128*128
        #pragma unroll
        for (int ich = 0; ich < 2; ++ich) {              // two 64-ic halves
            #pragma unroll
            for (int q = 0; q < 4; q++)
                GL2LDS16(hu + arow[q] + tapoff + ich * 64, As + ((size_t)(q * 512 + t)) * 8);
            #pragma unroll
            for (int q = 0; q < 2; q++)
                GL2LDS16(wtap + brow[q] + ich * 64, Bs + ((size_t)(q * 512 + t)) * 8);
            __syncthreads();
            #pragma unroll
            for (int ks = 0; ks < 2; ++ks) {
                bf16x8 av[4], bv[4];
                #pragma unroll
                for (int i = 0; i < 4; i++)
                    av[i] = *(const bf16x8*)&As[(wr * 64 + i * 16 + l15) * 64 + ks * 32 + kq * 8];
                #pragma unroll
                for (int j = 0; j < 4; j++)
                    bv[j] = *(const bf16x8*)&Bs[(wc * 64 + j * 16 + l15) * 64 + ks * 32 + kq * 8];
                #pragma unroll
                for (int i = 0; i < 4; i++)
                    #pragma unroll
                    for (int j = 0; j < 4; j++)
                        acc[i][j] = __builtin_amdgcn_mfma_f32_16x16x32_bf16(av[i], bv[j], acc[i][j], 0, 0, 0);
            }
            __syncthreads();
        }
    }

    // epilogue: plain stores to this group's partial slice (C/D: col=lane&15, row=(lane>>4)*4+reg)
    float* pg = pp + (size_t)g * 16000 * 128;
    #pragma unroll
    for (int i = 0; i < 4; i++) {
        int mbase = m0 + wr * 64 + i * 16 + kq * 4;
        #pragma unroll
        for (int j = 0; j < 4; j++) {
            int n = wc * 64 + j * 16 + l15;
            #pragma unroll
            for (int r = 0; r < 4; r++) {
                int m = mbase + r;
                if (m < 16000) pg[(size_t)m * 128 + n] = acc[i][j][r];
            }
        }
    }
}

// ============ reduce 8 pcaps partials -> p (coalesced float4) ============
__global__ void reduce_p(const float* __restrict__ pp, float* __restrict__ p) {
    int gid = blockIdx.x * 256 + threadIdx.x;        // 512000 float4, exact grid
    const float4* p4 = (const float4*)pp;
    float4 a = p4[gid];
    #pragma unroll
    for (int k = 1; k < 8; k++) {
        float4 b = p4[(size_t)k * 512000 + gid];
        a.x += b.x; a.y += b.y; a.z += b.z; a.w += b.w;
    }
    ((float4*)p)[gid] = a;
}

// ============ squash over capsule-dim 8 -> u[b][r][8] ============
__global__ void squash_u(const float* __restrict__ p, const float* __restrict__ pb,
                         float* __restrict__ u) {
    int gid = blockIdx.x * 256 + threadIdx.x;      // NB*RR = 256000, exact grid
    int b = gid / RR, r = gid % RR;
    int s = r % PSP, rq = r / PSP;
    float vals[8]; float ss = 0.f;
    #pragma unroll
    for (int i = 0; i < 8; i++) {
        int ch = i * 16 + rq;
        float pv = p[((size_t)b * PSP + s) * 128 + ch] + pb[ch];
        vals[i] = pv; ss += pv * pv;
    }
    float n = sqrtf(ss);
    float scale = ss / (1.f + ss) / (n + 1e-8f);
    #pragma unroll
    for (int i = 0; i < 8; i++) u[(size_t)gid * 8 + i] = vals[i] * scale;
}

// ============ priors[b][c][r][16] = sum_i u[b][r][i] * rw[c][r][i][16] ============
__global__ void priors_k(const float* __restrict__ u, const float* __restrict__ rw,
                         float* __restrict__ pri) {
    __shared__ float wl[16][132];
    int bx = blockIdx.x; int c = bx / 1000; int r0 = (bx % 1000) * 16;
    int t = threadIdx.x;
    const float4* src = (const float4*)(rw + ((size_t)c * RR + r0) * 128);
    #pragma unroll
    for (int q = 0; q < 8; q++) {
        int idx = q * 256 + t;
        int row = idx >> 5, c4 = idx & 31;
        *(float4*)&wl[row][c4 * 4] = src[idx];
    }
    __syncthreads();
    int bb = t >> 4, rl = t & 15;
    const float* up = u + ((size_t)bb * RR + r0 + rl) * 8;
    float4 u0 = *(const float4*)up, u1 = *(const float4*)(up + 4);
    float uu[8] = {u0.x, u0.y, u0.z, u0.w, u1.x, u1.y, u1.z, u1.w};
    float out[16];
    #pragma unroll
    for (int o = 0; o < 16; o++) out[o] = 0.f;
    #pragma unroll
    for (int i = 0; i < 8; i++)
        #pragma unroll
        for (int o = 0; o < 16; o++) out[o] += uu[i] * wl[rl][i * 16 + o];
    float* dst = pri + ((size_t)(bb * 2 + c) * RR + r0 + rl) * 16;
    #pragma unroll
    for (int q = 0; q < 4; q++)
        *(float4*)&dst[q * 4] = make_float4(out[q*4], out[q*4+1], out[q*4+2], out[q*4+3]);
}

// ============ routing: s[b][c][16] = sum_r softmax_c(logits) * priors ============
__global__ void route_s(const float* __restrict__ pri, const float* __restrict__ lg,
                        float* __restrict__ s) {
    int b = blockIdx.x, chunk = blockIdx.y;
    int t = threadIdx.x, o = t & 15, rl = t >> 4;
    float acc0 = 0.f, acc1 = 0.f;
    for (int j = 0; j < 40; j++) {
        int r = chunk * 640 + j * 16 + rl;
        float l0 = lg[(size_t)(b * 2 + 0) * RR + r];
        float l1 = lg[(size_t)(b * 2 + 1) * RR + r];
        float m = fmaxf(l0, l1);
        float e0 = __expf(l0 - m), e1 = __expf(l1 - m);
        float inv = 1.f / (e0 + e1);
        acc0 += (e0 * inv) * pri[((size_t)(b * 2 + 0) * RR + r) * 16 + o];
        acc1 += (e1 * inv) * pri[((size_t)(b * 2 + 1) * RR + r) * 16 + o];
    }
    __shared__ float red[2][16][17];
    red[0][rl][o] = acc0; red[1][rl][o] = acc1;
    __syncthreads();
    for (int step = 8; step >= 1; step >>= 1) {
        if (rl < step) {
            red[0][rl][o] += red[0][rl + step][o];
            red[1][rl][o] += red[1][rl + step][o];
        }
        __syncthreads();
    }
    if (rl == 0) {
        atomicAdd(&s[(b * 2 + 0) * 16 + o], red[0][0][o]);
        atomicAdd(&s[(b * 2 + 1) * 16 + o], red[1][0][o]);
    }
}

__global__ void squash_v(const float* __restrict__ s, float* __restrict__ v) {
    int t = threadIdx.x;            // 512 = 32 bc * 16 o
    int bc = t >> 4, o = t & 15;
    float ss = 0.f;
    #pragma unroll
    for (int i = 0; i < 16; i++) { float x = s[bc * 16 + i]; ss += x * x; }
    float n = sqrtf(ss);
    float sc = ss / (1.f + ss) / (n + 1e-8f);
    v[bc * 16 + o] = s[bc * 16 + o] * sc;
}

__global__ void route_logit(const float* __restrict__ pri, const float* __restrict__ v,
                            float* __restrict__ lg) {
    int gid = blockIdx.x * 256 + threadIdx.x;    // 512000 exact
    int bc = gid / RR;
    const float* pp = pri + (size_t)gid * 16;
    float dot = 0.f;
    #pragma unroll
    for (int o = 0; o < 16; o++) dot += pp[o] * v[bc * 16 + o];
    lg[gid] += dot;
}

// ============ classes + argmax mask -> d0[16][32], classes -> d_out[0:32] ============
__global__ void classes_mask(const float* __restrict__ v, float* __restrict__ out,
                             float* __restrict__ d0) {
    __shared__ float cls[32];
    int t = threadIdx.x;
    if (t < 32) {
        float ss = 0.f;
        #pragma unroll
        for (int i = 0; i < 16; i++) { float x = v[t * 16 + i]; ss += x * x; }
        float n = sqrtf(ss);
        cls[t] = n; out[t] = n;
    }
    __syncthreads();
    int b = t >> 5, k = t & 31, c = k >> 4;
    int win = (cls[b * 2 + 1] > cls[b * 2 + 0]) ? 1 : 0;
    d0[t] = (c == win) ? v[b * 32 + k] : 0.f;
}

// ============ decoder small layers (full-K, bias+relu) ============
template<int K>
__global__ void dec_small(const float* __restrict__ din, const float* __restrict__ W,
                          const float* __restrict__ bias, float* __restrict__ dout, int N) {
    __shared__ float dl[16 * K];
    int t = threadIdx.x;
    for (int i = t; i < 16 * K; i += 256) dl[i] = din[i];
    __syncthreads();
    int n = blockIdx.x * 256 + t;
    if (n >= N) return;
    float acc[16];
    float bv = bias[n];
    #pragma unroll
    for (int b = 0; b < 16; b++) acc[b] = bv;
    for (int k = 0; k < K; k++) {
        float w = W[(size_t)k * N + n];
        #pragma unroll
        for (int b = 0; b < 16; b++) acc[b] += dl[b * K + k] * w;
    }
    #pragma unroll
    for (int b = 0; b < 16; b++) dout[(size_t)b * N + n] = fmaxf(acc[b], 0.f);
}

// ============ decoder big layers: K-split partial GEMM, no atomics, float4 W ============
__global__ void dec_split(const float* __restrict__ din, const float* __restrict__ W,
                          float* __restrict__ part, int N, int K, int KC) {
    extern __shared__ float dl[];
    int t = threadIdx.x;
    int ky = blockIdx.y;
    int k0 = ky * KC;
    for (int i = t; i < 16 * KC; i += 256) {
        int b = i / KC, kk = i % KC;
        dl[i] = din[(size_t)b * K + k0 + kk];
    }
    __syncthreads();
    int n = blockIdx.x * 1024 + t * 4;
    if (n >= N) return;                       // N % 4 == 0, no straddle
    float4 acc[16];
    #pragma unroll
    for (int b = 0; b < 16; b++) acc[b] = make_float4(0.f, 0.f, 0.f, 0.f);
    const float* Wp = W + (size_t)k0 * N + n;
    for (int kk = 0; kk < KC; kk++) {
        float4 w = *(const float4*)&Wp[(size_t)kk * N];
        #pragma unroll
        for (int b = 0; b < 16; b++) {
            float dv = dl[b * KC + kk];
            acc[b].x += dv * w.x; acc[b].y += dv * w.y;
            acc[b].z += dv * w.z; acc[b].w += dv * w.w;
        }
    }
    #pragma unroll
    for (int b = 0; b < 16; b++)
        *(float4*)&part[((size_t)(ky * 16 + b)) * N + n] = acc[b];
}

// ============ sum 16 ky-partials + bias + activation ============
__global__ void bias_act_sum(const float* __restrict__ part, const float* __restrict__ bias,
                             float* __restrict__ out, int N, int total, int sigm) {
    int gid = blockIdx.x * 256 + threadIdx.x;
    if (gid >= total) return;
    int b = gid / N, n = gid % N;
    float x = bias[n];
    #pragma unroll
    for (int ky = 0; ky < 16; ky++)
        x += part[((size_t)(ky * 16 + b)) * N + n];
    out[gid] = sigm ? (1.f / (1.f + __expf(-x))) : fmaxf(x, 0.f);
}

// ================================================================
extern "C" void kernel_launch(void* const* d_in, const int* in_sizes, int n_in,
                              void* d_out, int out_size, void* d_ws, size_t ws_size,
                              hipStream_t stream) {
    const float* x        = (const float*)d_in[0];
    const float* conv1_w  = (const float*)d_in[1];
    const float* conv1_b  = (const float*)d_in[2];
    const float* pcaps_w  = (const float*)d_in[3];
    const float* pcaps_b  = (const float*)d_in[4];
    const float* route_w  = (const float*)d_in[5];
    const float* dec_w1   = (const float*)d_in[6];
    const float* dec_b1   = (const float*)d_in[7];
    const float* dec_w2   = (const float*)d_in[8];
    const float* dec_b2   = (const float*)d_in[9];
    const float* dec_w3   = (const float*)d_in[10];
    const float* dec_b3   = (const float*)d_in[11];
    const float* dec_w4   = (const float*)d_in[12];
    const float* dec_b4   = (const float*)d_in[13];
    float* out = (float*)d_out;

    float* ws = (float*)d_ws;
    __hip_bfloat16* w2 = (__hip_bfloat16*)(ws + OFF_WT);
    __hip_bfloat16* h  = (__hip_bfloat16*)(ws + OFF_H);
    float* p    = ws + OFF_P;
    float* u    = ws + OFF_U;
    float* pri  = ws + OFF_PRI;
    float* lg   = ws + OFF_LOG;
    float* s    = ws + OFF_S;
    float* v    = ws + OFF_V;
    float* d0   = ws + OFF_D0;
    float* d1   = ws + OFF_D1;
    float* d2   = ws + OFF_D2;
    float* d3   = ws + OFF_D3;
    float* d4   = ws + OFF_D4;
    float* pp   = ws + OFF_PP;
    float* d3p  = ws + OFF_D3P;
    float* d4p  = ws + OFF_D4P;

    // prep + conv1 (h in bf16 channel-last)
    prep_w2<<<dim3(23, 4, 128), 256, 0, stream>>>(pcaps_w, w2);
    conv1_relu<<<(SPTOT + 31) / 32, 256, 0, stream>>>(x, conv1_w, conv1_b, h);

    // pcaps conv: 256x128 MFMA tiles, K-split x8 (XCD-pinned), partials + reduce
    pcaps_mfma<<<504, 512, 0, stream>>>((const ushort*)h, (const ushort*)w2, pp);
    reduce_p<<<2000, 256, 0, stream>>>(pp, p);

    // squash -> u ; priors einsum
    squash_u<<<1000, 256, 0, stream>>>(p, pcaps_b, u);
    priors_k<<<2000, 256, 0, stream>>>(u, route_w, pri);

    // dynamic routing, 3 iterations
    hipMemsetAsync(lg, 0, (size_t)NB * NCAP * RR * sizeof(float), stream);
    for (int it = 0; it < 3; it++) {
        hipMemsetAsync(s, 0, 512 * sizeof(float), stream);
        route_s<<<dim3(16, 25), 256, 0, stream>>>(pri, lg, s);
        squash_v<<<1, 512, 0, stream>>>(s, v);
        if (it < 2) route_logit<<<2000, 256, 0, stream>>>(pri, v, lg);
    }

    // classes (output 0) + masked decoder input
    classes_mask<<<1, 512, 0, stream>>>(v, out, d0);

    // decoder
    dec_small<32><<<2, 256, 0, stream>>>(d0, dec_w1, dec_b1, d1, 512);
    dec_small<512><<<8, 256, 0, stream>>>(d1, dec_w2, dec_b2, d2, 2048);

    dec_split<<<dim3(10, 16), 256, 16 * 128 * sizeof(float), stream>>>(d2, dec_w3, d3p, 10240, 2048, 128);
    bias_act_sum<<<(16 * 10240 + 255) / 256, 256, 0, stream>>>(d3p, dec_b3, d3, 10240, 16 * 10240, 0);

    dec_split<<<dim3(27, 16), 256, 16 * 640 * sizeof(float), stream>>>(d3, dec_w4, d4p, 27000, 10240, 640);
    bias_act_sum<<<(16 * 27000 + 255) / 256, 256, 0, stream>>>(d4p, dec_b4, out + 32, 27000, 16 * 27000, 1);
}